// Round 8
// baseline (664.195 us; speedup 1.0000x reference)
//
#include <hip/hip_runtime.h>
#include <math.h>

#define BQ 4096
#define NMEM 32768
#define DD 512
#define TOPN 10
#define CB 256                   /* 128-col blocks over NMEM */
#define ENT 2048                 /* candidate entries per row = CB*8 */
#define NCF 16                   /* final candidates per row */
#define LK 6                     /* per-lane top-K in knn_select scan */
#define SSTR 132                 /* LDS score stride (words) in gemm_knn epilogue */
#define FINF 3.402823466e+38f
#define IMAX 0x7fffffff

typedef __attribute__((ext_vector_type(8))) short    bf16x8;
typedef __attribute__((ext_vector_type(4))) float    f32x4;

// ---------------- helpers ----------------
__device__ __forceinline__ unsigned short f2bf(float x) {
    unsigned int u = __float_as_uint(x);
    u += 0x7fffu + ((u >> 16) & 1u);          // round-to-nearest-even
    return (unsigned short)(u >> 16);
}
__device__ __forceinline__ void async_copy16(const void* gp, void* lp) {
    __builtin_amdgcn_global_load_lds(
        (const __attribute__((address_space(1))) void*)gp,
        (__attribute__((address_space(3))) void*)lp, 16, 0, 0);
}
__device__ __forceinline__ bool lt_si(float s, int j, float s2, int j2) {
    return (s < s2) || (s == s2 && j < j2);   // matches top_k tie-break
}
template<int KN>
__device__ __forceinline__ void topk_insert(float (&ts)[KN], int (&ti)[KN], float s, int j) {
    if (!lt_si(s, j, ts[KN-1], ti[KN-1])) return;
    #pragma unroll
    for (int p = KN-1; p > 0; --p) {
        if (lt_si(s, j, ts[p-1], ti[p-1])) { ts[p] = ts[p-1]; ti[p] = ti[p-1]; }
        else { ts[p] = s; ti[p] = j; return; }
    }
    ts[0] = s; ti[0] = j;
}

// ---------------- segmented cast: visit + 6 weight matrices in ONE dispatch ----------------
struct CastDesc {
    const float* in[7];
    unsigned short* out[7];
    int start[8];   // cumulative block starts, start[7] = total
};
__global__ __launch_bounds__(256) void cast_multi_kernel(CastDesc d) {
    int blk = blockIdx.x;
    int seg = 0;
    #pragma unroll
    for (int s = 0; s < 6; ++s) seg += (blk >= d.start[s + 1]) ? 1 : 0;
    int local = blk - d.start[seg];
    int i = (local * 256 + threadIdx.x) * 4;
    float4 v = *(const float4*)(d.in[seg] + i);
    ushort4 o;
    o.x = f2bf(v.x); o.y = f2bf(v.y); o.z = f2bf(v.z); o.w = f2bf(v.w);
    *(ushort4*)(d.out[seg] + i) = o;
}

// ---------------- fused fp32->bf16 cast (+ ||row||^2 for y==0) over Epat/Emed ----------------
__global__ __launch_bounds__(256) void cast_norm2_kernel(
        const float* __restrict__ inA, unsigned short* __restrict__ outA,
        const float* __restrict__ inB, unsigned short* __restrict__ outB,
        float* __restrict__ mnorm) {
    const float* in = blockIdx.y ? inB : inA;
    unsigned short* out = blockIdx.y ? outB : outA;
    int row = blockIdx.x * 4 + (threadIdx.x >> 6);
    int lane = threadIdx.x & 63;
    const float* r = in + (size_t)row * DD + lane * 8;
    float4 a = *(const float4*)r;
    float4 b = *(const float4*)(r + 4);
    ushort4 oa, ob;
    oa.x = f2bf(a.x); oa.y = f2bf(a.y); oa.z = f2bf(a.z); oa.w = f2bf(a.w);
    ob.x = f2bf(b.x); ob.y = f2bf(b.y); ob.z = f2bf(b.z); ob.w = f2bf(b.w);
    unsigned short* op = out + (size_t)row * DD + lane * 8;
    *(ushort4*)op = oa; *(ushort4*)(op + 4) = ob;
    if (blockIdx.y == 0) {
        float s = a.x*a.x + a.y*a.y + a.z*a.z + a.w*a.w
                + b.x*b.x + b.y*b.y + b.z*b.z + b.w*b.w;
        #pragma unroll
        for (int off = 32; off; off >>= 1) s += __shfl_xor(s, off, 64);
        if (lane == 0) mnorm[row] = s;
    }
}

// ---------------- fused kNN GEMM + per-block candidate selection ----------------
// m97-structure main loop. Scores = mnorm[col] - 2*dot are provably positive
// (mean ~512, 9-sigma floor ~196 for N(0,1) data), so packed key = raw fp32
// bits (clamped >=0, monotone under uint compare) & ~127 | 7-bit local col.
// 4 B/entry; block idx recovered from entry position. Per-(row, 64-col half)
// reducer keeps top-4 of 64 (round-4 lesson: no lane-level pruning).
__global__ __launch_bounds__(256) void gemm_knn_kernel(
        const unsigned short* __restrict__ Qb,   // [4096][512] bf16
        const unsigned short* __restrict__ Mb,   // [NMEM][512] bf16
        const float* __restrict__ mnorm,
        unsigned* __restrict__ cand_part) {      // [4096][ENT] packed keys
    __shared__ __align__(16) union {
        struct { unsigned short As[128 * 64]; unsigned short Bs[128 * 64]; } g; // 32 KB
        unsigned S[64 * SSTR];                                                  // 33 KB
    } sh;
    const int tid  = threadIdx.x;
    const int wave = tid >> 6, lane = tid & 63;
    const int quad = lane >> 4, c16 = lane & 15;
    const int m0 = blockIdx.y * 128, n0 = blockIdx.x * 128;
    const int wm0 = (wave >> 1) * 64, wn0 = (wave & 1) * 64;
    const int half = wave & 1;
    const int srow = wave * 32 + (lane >> 3);
    const int schunk = lane & 7;

    f32x4 acc[4][4] = {};

    for (int kt = 0; kt < DD; kt += 64) {
        __syncthreads();
        #pragma unroll
        for (int i = 0; i < 4; ++i) {
            const unsigned short* ga = Qb + (size_t)(m0 + srow + i * 8) * DD + kt + schunk * 8;
            async_copy16(ga, &sh.g.As[(wave * 32 + i * 8) * 64]);
            const unsigned short* gb = Mb + (size_t)(n0 + srow + i * 8) * DD + kt + schunk * 8;
            async_copy16(gb, &sh.g.Bs[(wave * 32 + i * 8) * 64]);
        }
        __syncthreads();
        #pragma unroll
        for (int ks = 0; ks < 64; ks += 32) {
            bf16x8 af[4], bff[4];
            #pragma unroll
            for (int mt = 0; mt < 4; ++mt)
                af[mt] = *(const bf16x8*)&sh.g.As[(wm0 + mt * 16 + c16) * 64 + ks + quad * 8];
            #pragma unroll
            for (int nt = 0; nt < 4; ++nt)
                bff[nt] = *(const bf16x8*)&sh.g.Bs[(wn0 + nt * 16 + c16) * 64 + ks + quad * 8];
            #pragma unroll
            for (int mt = 0; mt < 4; ++mt)
                #pragma unroll
                for (int nt = 0; nt < 4; ++nt)
                    acc[mt][nt] = __builtin_amdgcn_mfma_f32_16x16x32_bf16(
                        af[mt], bff[nt], acc[mt][nt], 0, 0, 0);
        }
    }

    const int cbase = n0 + wn0 + c16;
    float mn[4];
    #pragma unroll
    for (int nt = 0; nt < 4; ++nt) mn[nt] = mnorm[cbase + nt * 16];

    const int rrow = tid >> 1, rhalf = tid & 1;   // reducer identity
    unsigned q4[4] = {0xFFFFFFFFu, 0xFFFFFFFFu, 0xFFFFFFFFu, 0xFFFFFFFFu};

    __syncthreads();   // main-loop LDS reads done before aliasing As/Bs
    #pragma unroll
    for (int p = 0; p < 2; ++p) {
        #pragma unroll
        for (int mt = 0; mt < 4; ++mt)
            #pragma unroll
            for (int b = 0; b < 2; ++b) {
                const int nt = 2 * p + b;
                const int lcol = half * 64 + nt * 16 + c16;   // 7-bit local col
                uint4 w;
                #pragma unroll
                for (int r = 0; r < 4; ++r) {
                    float s = fmaxf(fmaf(-2.f, acc[mt][nt][r], mn[nt]), 0.f);
                    (&w.x)[r] = (__float_as_uint(s) & 0xFFFFFF80u) | (unsigned)lcol;
                }
                const int slot = half * 32 + b * 16 + c16;
                *(uint4*)&sh.S[slot * SSTR + wm0 + mt * 16 + quad * 4] = w;
            }
        __syncthreads();
        #pragma unroll
        for (int m = 0; m < 32; ++m) {
            unsigned nv = sh.S[(rhalf * 32 + m) * SSTR + rrow];
            #pragma unroll
            for (int i = 0; i < 4; ++i) {
                unsigned lo = min(q4[i], nv);
                nv = max(q4[i], nv);
                q4[i] = lo;
            }
        }
        __syncthreads();
    }

    *(uint4*)(cand_part + (size_t)(m0 + rrow) * ENT + blockIdx.x * 8 + rhalf * 4) =
        make_uint4(q4[0], q4[1], q4[2], q4[3]);
}

// ---------------- fused select: scan 2048 keys -> exact top-16 -> fp32 rescore -> top-10 ----
// One block (4 waves) per row. ROUND-7 FIX: each wave extracts top-16 (not 8)
// so any element with <16 wave-betters survives unconditionally; wave 0 then
// merges 64 -> exact top-16 of cand_part. True top-10 has <=~11 coarse-betters
// (9 exact + noise) < 16 -> zero statistical loss at this stage.
__global__ __launch_bounds__(256) void knn_select_kernel(
        const unsigned* __restrict__ cand_part,  // [4096][ENT] packed keys
        const float* __restrict__ Q, const float* __restrict__ Mm,
        const float* __restrict__ mnorm,
        int* __restrict__ knn_idx) {
    const int row = blockIdx.x;
    const int wave = threadIdx.x >> 6, lane = threadIdx.x & 63;
    __shared__ unsigned sk[64];
    __shared__ int      sc[64];
    __shared__ int      ids[NCF];
    __shared__ float    d2s[NCF];

    // phase A: per-lane top-6 over this wave's 512 keys (8/lane, uint4 loads)
    unsigned ks[LK]; int ti[LK];
    #pragma unroll
    for (int q = 0; q < LK; ++q) { ks[q] = 0xFFFFFFFFu; ti[q] = IMAX; }
    const uint4* p4 = (const uint4*)(cand_part + (size_t)row * ENT) + wave * 128;
    #pragma unroll
    for (int i = 0; i < 2; ++i) {
        uint4 v = p4[lane + 64 * i];
        #pragma unroll
        for (int e = 0; e < 4; ++e) {
            unsigned k = (&v.x)[e];
            int pos = wave * 512 + (lane + 64 * i) * 4 + e;
            int gcol = (pos >> 3) * 128 + (int)(k & 127u);
            bool cm[LK];
            #pragma unroll
            for (int q = 0; q < LK; ++q) cm[q] = k < ks[q];
            #pragma unroll
            for (int q = LK - 1; q > 0; --q) {
                unsigned tns = cm[q] ? k : ks[q];  int tni = cm[q] ? gcol : ti[q];
                ks[q] = cm[q-1] ? ks[q-1] : tns;
                ti[q] = cm[q-1] ? ti[q-1] : tni;
            }
            ks[0] = cm[0] ? k : ks[0];
            ti[0] = cm[0] ? gcol : ti[0];
        }
    }
    // phase B: per-wave top-16 via argmin extraction
    #pragma unroll
    for (int r = 0; r < NCF; ++r) {
        unsigned mk = ks[0]; int mi = ti[0];
        #pragma unroll
        for (int off = 1; off < 64; off <<= 1) {
            unsigned ok = (unsigned)__shfl_xor((int)mk, off, 64);
            int      oi = __shfl_xor(mi, off, 64);
            bool t = (ok < mk) || (ok == mk && oi < mi);
            mk = t ? ok : mk; mi = t ? oi : mi;
        }
        bool win = (ks[0] == mk) && (ti[0] == mi);
        #pragma unroll
        for (int q = 0; q < LK - 1; ++q) {
            ks[q] = win ? ks[q+1] : ks[q];
            ti[q] = win ? ti[q+1] : ti[q];
        }
        ks[LK-1] = win ? 0xFFFFFFFFu : ks[LK-1];
        ti[LK-1] = win ? IMAX : ti[LK-1];
        if (lane == r) { sk[wave * NCF + r] = mk; sc[wave * NCF + r] = mi; }
    }
    __syncthreads();
    // phase C: wave 0 merges 64 -> exact top-16
    if (wave == 0) {
        unsigned myk = sk[lane];
        int      myc = sc[lane];
        #pragma unroll
        for (int r = 0; r < NCF; ++r) {
            unsigned mk = myk; int mi = myc;
            #pragma unroll
            for (int off = 1; off < 64; off <<= 1) {
                unsigned ok = (unsigned)__shfl_xor((int)mk, off, 64);
                int      oi = __shfl_xor(mi, off, 64);
                bool t = (ok < mk) || (ok == mk && oi < mi);
                mk = t ? ok : mk; mi = t ? oi : mi;
            }
            bool win = (myk == mk) && (myc == mi);
            myk = win ? 0xFFFFFFFFu : myk;
            myc = win ? IMAX : myc;
            if (lane == r) ids[r] = mi;
        }
    }
    __syncthreads();
    // phase D: exact fp32 rescore of 16 candidates
    float4 q0 = *(const float4*)(Q + (size_t)row * DD + lane * 8);
    float4 q1 = *(const float4*)(Q + (size_t)row * DD + lane * 8 + 4);
    for (int c = wave; c < NCF; c += 4) {
        int j = ids[c];
        const float* mr = Mm + (size_t)j * DD;
        float4 m0 = *(const float4*)(mr + lane * 8);
        float4 m1 = *(const float4*)(mr + lane * 8 + 4);
        float dot = q0.x*m0.x + q0.y*m0.y + q0.z*m0.z + q0.w*m0.w
                  + q1.x*m1.x + q1.y*m1.y + q1.z*m1.z + q1.w*m1.w;
        #pragma unroll
        for (int off = 32; off; off >>= 1) dot += __shfl_xor(dot, off, 64);
        if (lane == 0) d2s[c] = fmaf(-2.f, dot, mnorm[j]);
    }
    __syncthreads();
    // phase E: top-10 (exact lexicographic)
    if (threadIdx.x == 0) {
        float ts[TOPN]; int tj[TOPN];
        #pragma unroll
        for (int p = 0; p < TOPN; ++p) { ts[p] = FINF; tj[p] = IMAX; }
        for (int c = 0; c < NCF; ++c) topk_insert<TOPN>(ts, tj, d2s[c], ids[c]);
        #pragma unroll
        for (int p = 0; p < TOPN; ++p) knn_idx[row * TOPN + p] = tj[p];
    }
}

// ---------------- unified bf16 MFMA GEMM (m97 structure) ----------------
template<int ACT, int OUT_BF16>
__global__ __launch_bounds__(256) void gemm_bf16_nt(
        const unsigned short* __restrict__ A,
        const unsigned short* __restrict__ B,
        const float* __restrict__ bias,
        void* __restrict__ Cout, int ldc) {
    __shared__ __align__(16) unsigned short As[128 * 64];
    __shared__ __align__(16) unsigned short Bs[128 * 64];
    const int tid  = threadIdx.x;
    const int wave = tid >> 6, lane = tid & 63;
    const int quad = lane >> 4, c16 = lane & 15;
    const int m0 = blockIdx.y * 128, n0 = blockIdx.x * 128;
    const int wm0 = (wave >> 1) * 64, wn0 = (wave & 1) * 64;
    const int srow = wave * 32 + (lane >> 3);
    const int schunk = lane & 7;

    f32x4 acc[4][4] = {};

    for (int kt = 0; kt < DD; kt += 64) {
        __syncthreads();
        #pragma unroll
        for (int i = 0; i < 4; ++i) {
            const unsigned short* ga = A + (size_t)(m0 + srow + i * 8) * DD + kt + schunk * 8;
            async_copy16(ga, &As[(wave * 32 + i * 8) * 64]);
            const unsigned short* gb = B + (size_t)(n0 + srow + i * 8) * DD + kt + schunk * 8;
            async_copy16(gb, &Bs[(wave * 32 + i * 8) * 64]);
        }
        __syncthreads();
        #pragma unroll
        for (int ks = 0; ks < 64; ks += 32) {
            bf16x8 af[4], bff[4];
            #pragma unroll
            for (int mt = 0; mt < 4; ++mt)
                af[mt] = *(const bf16x8*)&As[(wm0 + mt * 16 + c16) * 64 + ks + quad * 8];
            #pragma unroll
            for (int nt = 0; nt < 4; ++nt)
                bff[nt] = *(const bf16x8*)&Bs[(wn0 + nt * 16 + c16) * 64 + ks + quad * 8];
            #pragma unroll
            for (int mt = 0; mt < 4; ++mt)
                #pragma unroll
                for (int nt = 0; nt < 4; ++nt)
                    acc[mt][nt] = __builtin_amdgcn_mfma_f32_16x16x32_bf16(
                        af[mt], bff[nt], acc[mt][nt], 0, 0, 0);
        }
    }
    #pragma unroll
    for (int nt = 0; nt < 4; ++nt) {
        int ncol = n0 + wn0 + nt * 16 + c16;
        float bv = bias[ncol];
        #pragma unroll
        for (int mt = 0; mt < 4; ++mt) {
            size_t rbase = (size_t)(m0 + wm0 + mt * 16 + quad * 4) * ldc + ncol;
            #pragma unroll
            for (int r = 0; r < 4; ++r) {
                float v = acc[mt][nt][r] + bv;
                if (ACT == 1) v = v >= 0.f ? v : 0.01f * v;
                if (OUT_BF16) ((unsigned short*)Cout)[rbase + (size_t)r * ldc] = f2bf(v);
                else          ((float*)Cout)[rbase + (size_t)r * ldc] = v;
            }
        }
    }
}

// ---------------- K/V/q projections in ONE dispatch (z selects) ----------------
struct G3 {
    const unsigned short* A[3];
    const unsigned short* B[3];
    const float* bias[3];
    void* C[3];
    int ylim[3];
    int obf[3];
};
__global__ __launch_bounds__(256) void gemm3_kernel(G3 g) {
    const int z = blockIdx.z;
    if (blockIdx.y >= g.ylim[z]) return;
    __shared__ __align__(16) unsigned short As[128 * 64];
    __shared__ __align__(16) unsigned short Bs[128 * 64];
    const unsigned short* A = g.A[z];
    const unsigned short* B = g.B[z];
    const int tid  = threadIdx.x;
    const int wave = tid >> 6, lane = tid & 63;
    const int quad = lane >> 4, c16 = lane & 15;
    const int m0 = blockIdx.y * 128, n0 = blockIdx.x * 128;
    const int wm0 = (wave >> 1) * 64, wn0 = (wave & 1) * 64;
    const int srow = wave * 32 + (lane >> 3);
    const int schunk = lane & 7;

    f32x4 acc[4][4] = {};

    for (int kt = 0; kt < DD; kt += 64) {
        __syncthreads();
        #pragma unroll
        for (int i = 0; i < 4; ++i) {
            const unsigned short* ga = A + (size_t)(m0 + srow + i * 8) * DD + kt + schunk * 8;
            async_copy16(ga, &As[(wave * 32 + i * 8) * 64]);
            const unsigned short* gb = B + (size_t)(n0 + srow + i * 8) * DD + kt + schunk * 8;
            async_copy16(gb, &Bs[(wave * 32 + i * 8) * 64]);
        }
        __syncthreads();
        #pragma unroll
        for (int ks = 0; ks < 64; ks += 32) {
            bf16x8 af[4], bff[4];
            #pragma unroll
            for (int mt = 0; mt < 4; ++mt)
                af[mt] = *(const bf16x8*)&As[(wm0 + mt * 16 + c16) * 64 + ks + quad * 8];
            #pragma unroll
            for (int nt = 0; nt < 4; ++nt)
                bff[nt] = *(const bf16x8*)&Bs[(wn0 + nt * 16 + c16) * 64 + ks + quad * 8];
            #pragma unroll
            for (int mt = 0; mt < 4; ++mt)
                #pragma unroll
                for (int nt = 0; nt < 4; ++nt)
                    acc[mt][nt] = __builtin_amdgcn_mfma_f32_16x16x32_bf16(
                        af[mt], bff[nt], acc[mt][nt], 0, 0, 0);
        }
    }
    const int obf = g.obf[z];
    #pragma unroll
    for (int nt = 0; nt < 4; ++nt) {
        int ncol = n0 + wn0 + nt * 16 + c16;
        float bv = g.bias[z][ncol];
        #pragma unroll
        for (int mt = 0; mt < 4; ++mt) {
            size_t rbase = (size_t)(m0 + wm0 + mt * 16 + quad * 4) * DD + ncol;
            #pragma unroll
            for (int r = 0; r < 4; ++r) {
                float v = acc[mt][nt][r] + bv;
                if (obf) ((unsigned short*)g.C[z])[rbase + (size_t)r * DD] = f2bf(v);
                else     ((float*)g.C[z])[rbase + (size_t)r * DD] = v;
            }
        }
    }
}

// ---------------- attention: one block per query row, one wave per head ----------------
__global__ __launch_bounds__(512) void attn_kernel(
        const float* __restrict__ qh, const unsigned short* __restrict__ Kall,
        const unsigned short* __restrict__ Vall, const int* __restrict__ knn_idx,
        unsigned short* __restrict__ ctx_b) {
    const int b = blockIdx.x;
    const int h = threadIdx.x >> 6;
    const int l = threadIdx.x & 63;
    const int col = (h << 6) + l;
    int idxs[TOPN];
    #pragma unroll
    for (int n = 0; n < TOPN; ++n) idxs[n] = knn_idx[b * TOPN + n];
    const float q = qh[(size_t)b * DD + col];
    float sc[TOPN];
    #pragma unroll
    for (int n = 0; n < TOPN; ++n) {
        float p = q * __uint_as_float((unsigned)Kall[(size_t)idxs[n] * DD + col] << 16);
        #pragma unroll
        for (int off = 32; off; off >>= 1) p += __shfl_xor(p, off, 64);
        sc[n] = p * 0.125f;
    }
    float mx = sc[0];
    #pragma unroll
    for (int n = 1; n < TOPN; ++n) mx = fmaxf(mx, sc[n]);
    float se = 0.f;
    #pragma unroll
    for (int n = 0; n < TOPN; ++n) { sc[n] = expf(sc[n] - mx); se += sc[n]; }
    const float inv = 1.f / se;
    float o = 0.f;
    #pragma unroll
    for (int n = 0; n < TOPN; ++n)
        o = fmaf(sc[n] * inv,
                 __uint_as_float((unsigned)Vall[(size_t)idxs[n] * DD + col] << 16), o);
    ctx_b[(size_t)b * DD + col] = f2bf(o);
}

// ---------------- residual add + layernorm (optional bf16 secondary output) ----------------
template<int EMIT_BF16>
__global__ __launch_bounds__(256) void add_ln_kernel(
        const float* __restrict__ X, const float* __restrict__ Y,
        const float* __restrict__ g, const float* __restrict__ be,
        float* __restrict__ out, unsigned short* __restrict__ out_b) {
    const int row = blockIdx.x;
    const int t = threadIdx.x;
    const size_t base = (size_t)row * DD;
    float v0 = X[base + t]       + Y[base + t];
    float v1 = X[base + 256 + t] + Y[base + 256 + t];
    float s = v0 + v1, sq = v0 * v0 + v1 * v1;
    #pragma unroll
    for (int off = 32; off; off >>= 1) { s += __shfl_xor(s, off, 64); sq += __shfl_xor(sq, off, 64); }
    __shared__ float rs[4], rq[4];
    const int w = t >> 6, l = t & 63;
    if (l == 0) { rs[w] = s; rq[w] = sq; }
    __syncthreads();
    float tot  = rs[0] + rs[1] + rs[2] + rs[3];
    float totq = rq[0] + rq[1] + rq[2] + rq[3];
    float mu = tot * (1.f / DD);
    float var = totq * (1.f / DD) - mu * mu;
    float rstd = rsqrtf(var + 1e-5f);
    float o0 = (v0 - mu) * rstd * g[t]       + be[t];
    float o1 = (v1 - mu) * rstd * g[256 + t] + be[256 + t];
    out[base + t] = o0;
    out[base + 256 + t] = o1;
    if (EMIT_BF16) {
        out_b[base + t] = f2bf(o0);
        out_b[base + 256 + t] = f2bf(o1);
    }
}

// ---------------- launch ----------------
extern "C" void kernel_launch(void* const* d_in, const int* in_sizes, int n_in,
                              void* d_out, int out_size, void* d_ws, size_t ws_size,
                              hipStream_t stream) {
    const float* visit = (const float*)d_in[0];
    const float* Epat  = (const float*)d_in[1];
    const float* Emed  = (const float*)d_in[2];
    const float* Wq = (const float*)d_in[3];
    const float* Wk = (const float*)d_in[4];
    const float* Wv = (const float*)d_in[5];
    const float* bq = (const float*)d_in[6];
    const float* bk = (const float*)d_in[7];
    const float* bv = (const float*)d_in[8];
    const float* Wo = (const float*)d_in[9];
    const float* bo = (const float*)d_in[10];
    const float* W1 = (const float*)d_in[11];
    const float* b1 = (const float*)d_in[12];
    const float* W2 = (const float*)d_in[13];
    const float* b2 = (const float*)d_in[14];
    const float* ln1g = (const float*)d_in[15];
    const float* ln1b = (const float*)d_in[16];
    const float* ln2g = (const float*)d_in[17];
    const float* ln2b = (const float*)d_in[18];
    float* out = (float*)d_out;

    // ---- workspace layout, ~174 MB peak ----
    char* base = (char*)d_ws;
    const size_t MB = 1u << 20;
    float* mnorm   = (float*)(base);                    // 128 KB
    int*   knn_idx = (int*)  (base + 2*MB);             // 160 KB
    float* qh      = (float*)(base + 3*MB);             // 8 MB
    float* attn_o  = qh;                                // alias: qh dead after attn
    float* x1      = (float*)(base + 11*MB);            // 8 MB
    float* ff      = (float*)(base + 19*MB);            // 8 MB
    unsigned short* Qb    = (unsigned short*)(base + 27*MB);  // 4 MB (visit bf16)
    unsigned short* ctx_b = (unsigned short*)(base + 31*MB);  // 4 MB
    unsigned short* x1_b  = (unsigned short*)(base + 35*MB);  // 4 MB
    unsigned short* h1_b  = (unsigned short*)(base + 39*MB);  // 4 MB
    unsigned short* Wq_b  = (unsigned short*)(base + 43*MB);  // 6 x 512 KB
    unsigned short* Wk_b  = Wq_b + 262144;
    unsigned short* Wv_b  = Wk_b + 262144;
    unsigned short* Wo_b  = Wv_b + 262144;
    unsigned short* W1_b  = Wo_b + 262144;
    unsigned short* W2_b  = W1_b + 262144;
    unsigned short* Mb     = (unsigned short*)(base + 46*MB); // 32 MB (Epat bf16)
    unsigned short* Emed_b = (unsigned short*)(base + 78*MB); // 32 MB
    // K|V region (64 MB bf16); cand_part (32 MB) aliases Kall during kNN phase
    unsigned short* Kall = (unsigned short*)(base + 110*MB);  // 32 MB
    unsigned short* Vall = Kall + (size_t)NMEM * DD;          // 32 MB
    unsigned* cand_part = (unsigned*)Kall;                    // alias (kNN only)

    // ---- casts + norms (2 dispatches total) ----
    cast_norm2_kernel<<<dim3(NMEM / 4, 2), 256, 0, stream>>>(Epat, Mb, Emed, Emed_b, mnorm);
    CastDesc cd;
    cd.in[0] = visit; cd.out[0] = Qb;
    cd.in[1] = Wq; cd.in[2] = Wk; cd.in[3] = Wv; cd.in[4] = Wo; cd.in[5] = W1; cd.in[6] = W2;
    cd.out[1] = Wq_b; cd.out[2] = Wk_b; cd.out[3] = Wv_b; cd.out[4] = Wo_b; cd.out[5] = W1_b; cd.out[6] = W2_b;
    cd.start[0] = 0; cd.start[1] = 2048;
    for (int s = 2; s <= 7; ++s) cd.start[s] = cd.start[s-1] + 256;
    cast_multi_kernel<<<cd.start[7], 256, 0, stream>>>(cd);

    // ---- kNN: fused MFMA scores + selection -> fused merge+rescore ----
    gemm_knn_kernel<<<dim3(CB, BQ / 128), 256, 0, stream>>>(Qb, Mb, mnorm, cand_part);
    knn_select_kernel<<<BQ, 256, 0, stream>>>(cand_part, visit, Epat, mnorm, knn_idx);

    // ---- K/V/q projections in one dispatch (Kall write overwrites cand_part, now dead)
    G3 g3;
    g3.A[0] = Mb;     g3.B[0] = Wk_b; g3.bias[0] = bk; g3.C[0] = Kall; g3.ylim[0] = NMEM/128; g3.obf[0] = 1;
    g3.A[1] = Emed_b; g3.B[1] = Wv_b; g3.bias[1] = bv; g3.C[1] = Vall; g3.ylim[1] = NMEM/128; g3.obf[1] = 1;
    g3.A[2] = Qb;     g3.B[2] = Wq_b; g3.bias[2] = bq; g3.C[2] = qh;   g3.ylim[2] = BQ/128;   g3.obf[2] = 0;
    gemm3_kernel<<<dim3(4, NMEM / 128, 3), 256, 0, stream>>>(g3);

    attn_kernel<<<BQ, 512, 0, stream>>>(qh, Kall, Vall, knn_idx, ctx_b);

    gemm_bf16_nt<0,0><<<dim3(4, BQ / 128), 256, 0, stream>>>(ctx_b, Wo_b, bo, attn_o, DD);
    add_ln_kernel<1><<<BQ, 256, 0, stream>>>(visit, attn_o, ln1g, ln1b, x1, x1_b);
    gemm_bf16_nt<1,1><<<dim3(4, BQ / 128), 256, 0, stream>>>(x1_b, W1_b, b1, h1_b, DD);
    gemm_bf16_nt<0,0><<<dim3(4, BQ / 128), 256, 0, stream>>>(h1_b, W2_b, b2, ff,   DD);
    add_ln_kernel<0><<<BQ, 256, 0, stream>>>(x1, ff, ln2g, ln2b, out, nullptr);
}

// Round 9
// 598.894 us; speedup vs baseline: 1.1090x; 1.1090x over previous
//
#include <hip/hip_runtime.h>
#include <math.h>

#define BQ 4096
#define NMEM 32768
#define DD 512
#define TOPN 10
#define CB 256                   /* 128-col blocks over NMEM */
#define ENT 2048                 /* candidate entries per row = CB*8 */
#define NCF 16                   /* final candidates per row */
#define LK 6                     /* per-lane top-K in knn_select scan */
#define SSTR 132                 /* LDS score stride (words) in gemm_knn epilogue */
#define FINF 3.402823466e+38f
#define IMAX 0x7fffffff

typedef __attribute__((ext_vector_type(8))) short    bf16x8;
typedef __attribute__((ext_vector_type(4))) float    f32x4;

// ---------------- helpers ----------------
__device__ __forceinline__ unsigned short f2bf(float x) {
    unsigned int u = __float_as_uint(x);
    u += 0x7fffu + ((u >> 16) & 1u);          // round-to-nearest-even
    return (unsigned short)(u >> 16);
}
__device__ __forceinline__ void async_copy16(const void* gp, void* lp) {
    __builtin_amdgcn_global_load_lds(
        (const __attribute__((address_space(1))) void*)gp,
        (__attribute__((address_space(3))) void*)lp, 16, 0, 0);
}
__device__ __forceinline__ bool lt_si(float s, int j, float s2, int j2) {
    return (s < s2) || (s == s2 && j < j2);   // matches top_k tie-break
}
template<int KN>
__device__ __forceinline__ void topk_insert(float (&ts)[KN], int (&ti)[KN], float s, int j) {
    if (!lt_si(s, j, ts[KN-1], ti[KN-1])) return;
    #pragma unroll
    for (int p = KN-1; p > 0; --p) {
        if (lt_si(s, j, ts[p-1], ti[p-1])) { ts[p] = ts[p-1]; ti[p] = ti[p-1]; }
        else { ts[p] = s; ti[p] = j; return; }
    }
    ts[0] = s; ti[0] = j;
}

// ---------------- segmented cast: visit + 6 weight matrices in ONE dispatch ----------------
struct CastDesc {
    const float* in[7];
    unsigned short* out[7];
    int start[8];   // cumulative block starts, start[7] = total
};
__global__ __launch_bounds__(256) void cast_multi_kernel(CastDesc d) {
    int blk = blockIdx.x;
    int seg = 0;
    #pragma unroll
    for (int s = 0; s < 6; ++s) seg += (blk >= d.start[s + 1]) ? 1 : 0;
    int local = blk - d.start[seg];
    int i = (local * 256 + threadIdx.x) * 4;
    float4 v = *(const float4*)(d.in[seg] + i);
    ushort4 o;
    o.x = f2bf(v.x); o.y = f2bf(v.y); o.z = f2bf(v.z); o.w = f2bf(v.w);
    *(ushort4*)(d.out[seg] + i) = o;
}

// ---------------- fused fp32->bf16 cast (+ ||row||^2 for y==0) over Epat/Emed ----------------
__global__ __launch_bounds__(256) void cast_norm2_kernel(
        const float* __restrict__ inA, unsigned short* __restrict__ outA,
        const float* __restrict__ inB, unsigned short* __restrict__ outB,
        float* __restrict__ mnorm) {
    const float* in = blockIdx.y ? inB : inA;
    unsigned short* out = blockIdx.y ? outB : outA;
    int row = blockIdx.x * 4 + (threadIdx.x >> 6);
    int lane = threadIdx.x & 63;
    const float* r = in + (size_t)row * DD + lane * 8;
    float4 a = *(const float4*)r;
    float4 b = *(const float4*)(r + 4);
    ushort4 oa, ob;
    oa.x = f2bf(a.x); oa.y = f2bf(a.y); oa.z = f2bf(a.z); oa.w = f2bf(a.w);
    ob.x = f2bf(b.x); ob.y = f2bf(b.y); ob.z = f2bf(b.z); ob.w = f2bf(b.w);
    unsigned short* op = out + (size_t)row * DD + lane * 8;
    *(ushort4*)op = oa; *(ushort4*)(op + 4) = ob;
    if (blockIdx.y == 0) {
        float s = a.x*a.x + a.y*a.y + a.z*a.z + a.w*a.w
                + b.x*b.x + b.y*b.y + b.z*b.z + b.w*b.w;
        #pragma unroll
        for (int off = 32; off; off >>= 1) s += __shfl_xor(s, off, 64);
        if (lane == 0) mnorm[row] = s;
    }
}

// ======== XOR-swizzled LDS GEMM core ========
// Round-9: LDS 16B-chunk index is XORed with (row & 7).  The global_load_lds
// DMA has a fixed lane->LDS mapping (base + lane*16B), so the swizzle is done
// by permuting each lane's GLOBAL chunk (free: 2 VALU, coalescing intact —
// permutation stays within each row's 128B segment).  Readers XOR the chunk
// with c16&7.  Bank group becomes 4*(quad ^ (c16&7)): 8 lanes per 4-bank
// group = 8 words/bank = the b128 minimum -> main-loop conflict-free
// (was 16 words/bank = 2x serialization, SQ_LDS_BANK_CONFLICT 5.45e7).

// ---------------- fused kNN GEMM + per-block candidate selection ----------------
__global__ __launch_bounds__(256) void gemm_knn_kernel(
        const unsigned short* __restrict__ Qb,   // [4096][512] bf16
        const unsigned short* __restrict__ Mb,   // [NMEM][512] bf16
        const float* __restrict__ mnorm,
        unsigned* __restrict__ cand_part) {      // [4096][ENT] packed keys
    __shared__ __align__(16) union {
        struct { unsigned short As[128 * 64]; unsigned short Bs[128 * 64]; } g; // 32 KB
        unsigned S[64 * SSTR];                                                  // 33 KB
    } sh;
    const int tid  = threadIdx.x;
    const int wave = tid >> 6, lane = tid & 63;
    const int quad = lane >> 4, c16 = lane & 15;
    const int m0 = blockIdx.y * 128, n0 = blockIdx.x * 128;
    const int wm0 = (wave >> 1) * 64, wn0 = (wave & 1) * 64;
    const int half = wave & 1;
    const int srow = wave * 32 + (lane >> 3);
    const int schunk = (lane & 7) ^ ((lane >> 3) & 7);   // swizzled global chunk
    const int xsw = c16 & 7;                              // reader swizzle key

    f32x4 acc[4][4] = {};

    for (int kt = 0; kt < DD; kt += 64) {
        __syncthreads();
        #pragma unroll
        for (int i = 0; i < 4; ++i) {
            const unsigned short* ga = Qb + (size_t)(m0 + srow + i * 8) * DD + kt + schunk * 8;
            async_copy16(ga, &sh.g.As[(wave * 32 + i * 8) * 64]);
            const unsigned short* gb = Mb + (size_t)(n0 + srow + i * 8) * DD + kt + schunk * 8;
            async_copy16(gb, &sh.g.Bs[(wave * 32 + i * 8) * 64]);
        }
        __syncthreads();
        #pragma unroll
        for (int ks = 0; ks < 64; ks += 32) {
            const int coff = (((ks >> 3) + quad) ^ xsw) << 3;
            bf16x8 af[4], bff[4];
            #pragma unroll
            for (int mt = 0; mt < 4; ++mt)
                af[mt] = *(const bf16x8*)&sh.g.As[(wm0 + mt * 16 + c16) * 64 + coff];
            #pragma unroll
            for (int nt = 0; nt < 4; ++nt)
                bff[nt] = *(const bf16x8*)&sh.g.Bs[(wn0 + nt * 16 + c16) * 64 + coff];
            #pragma unroll
            for (int mt = 0; mt < 4; ++mt)
                #pragma unroll
                for (int nt = 0; nt < 4; ++nt)
                    acc[mt][nt] = __builtin_amdgcn_mfma_f32_16x16x32_bf16(
                        af[mt], bff[nt], acc[mt][nt], 0, 0, 0);
        }
    }

    const int cbase = n0 + wn0 + c16;
    float mn[4];
    #pragma unroll
    for (int nt = 0; nt < 4; ++nt) mn[nt] = mnorm[cbase + nt * 16];

    const int rrow = tid >> 1, rhalf = tid & 1;   // reducer identity
    unsigned q4[4] = {0xFFFFFFFFu, 0xFFFFFFFFu, 0xFFFFFFFFu, 0xFFFFFFFFu};

    __syncthreads();   // main-loop LDS reads done before aliasing As/Bs
    #pragma unroll
    for (int p = 0; p < 2; ++p) {
        #pragma unroll
        for (int mt = 0; mt < 4; ++mt)
            #pragma unroll
            for (int b = 0; b < 2; ++b) {
                const int nt = 2 * p + b;
                const int lcol = half * 64 + nt * 16 + c16;   // 7-bit local col
                uint4 w;
                #pragma unroll
                for (int r = 0; r < 4; ++r) {
                    float s = fmaxf(fmaf(-2.f, acc[mt][nt][r], mn[nt]), 0.f);
                    (&w.x)[r] = (__float_as_uint(s) & 0xFFFFFF80u) | (unsigned)lcol;
                }
                const int slot = half * 32 + b * 16 + c16;
                *(uint4*)&sh.S[slot * SSTR + wm0 + mt * 16 + quad * 4] = w;
            }
        __syncthreads();
        #pragma unroll
        for (int m = 0; m < 32; ++m) {
            unsigned nv = sh.S[(rhalf * 32 + m) * SSTR + rrow];
            #pragma unroll
            for (int i = 0; i < 4; ++i) {
                unsigned lo = min(q4[i], nv);
                nv = max(q4[i], nv);
                q4[i] = lo;
            }
        }
        __syncthreads();
    }

    *(uint4*)(cand_part + (size_t)(m0 + rrow) * ENT + blockIdx.x * 8 + rhalf * 4) =
        make_uint4(q4[0], q4[1], q4[2], q4[3]);
}

// ---------------- fused select: scan 2048 keys -> exact top-16 -> fp32 rescore -> top-10 ----
// One block (4 waves) per row. Each wave extracts top-16 (round-7 lesson:
// per-wave cap must be >= global survivor count); wave 0 merges 64 -> exact
// top-16 of cand_part; exact fp32 rescore -> top-10.
__global__ __launch_bounds__(256) void knn_select_kernel(
        const unsigned* __restrict__ cand_part,  // [4096][ENT] packed keys
        const float* __restrict__ Q, const float* __restrict__ Mm,
        const float* __restrict__ mnorm,
        int* __restrict__ knn_idx) {
    const int row = blockIdx.x;
    const int wave = threadIdx.x >> 6, lane = threadIdx.x & 63;
    __shared__ unsigned sk[64];
    __shared__ int      sc[64];
    __shared__ int      ids[NCF];
    __shared__ float    d2s[NCF];

    // phase A: per-lane top-6 over this wave's 512 keys (8/lane, uint4 loads)
    unsigned ks[LK]; int ti[LK];
    #pragma unroll
    for (int q = 0; q < LK; ++q) { ks[q] = 0xFFFFFFFFu; ti[q] = IMAX; }
    const uint4* p4 = (const uint4*)(cand_part + (size_t)row * ENT) + wave * 128;
    #pragma unroll
    for (int i = 0; i < 2; ++i) {
        uint4 v = p4[lane + 64 * i];
        #pragma unroll
        for (int e = 0; e < 4; ++e) {
            unsigned k = (&v.x)[e];
            int pos = wave * 512 + (lane + 64 * i) * 4 + e;
            int gcol = (pos >> 3) * 128 + (int)(k & 127u);
            bool cm[LK];
            #pragma unroll
            for (int q = 0; q < LK; ++q) cm[q] = k < ks[q];
            #pragma unroll
            for (int q = LK - 1; q > 0; --q) {
                unsigned tns = cm[q] ? k : ks[q];  int tni = cm[q] ? gcol : ti[q];
                ks[q] = cm[q-1] ? ks[q-1] : tns;
                ti[q] = cm[q-1] ? ti[q-1] : tni;
            }
            ks[0] = cm[0] ? k : ks[0];
            ti[0] = cm[0] ? gcol : ti[0];
        }
    }
    // phase B: per-wave top-16 via argmin extraction
    #pragma unroll
    for (int r = 0; r < NCF; ++r) {
        unsigned mk = ks[0]; int mi = ti[0];
        #pragma unroll
        for (int off = 1; off < 64; off <<= 1) {
            unsigned ok = (unsigned)__shfl_xor((int)mk, off, 64);
            int      oi = __shfl_xor(mi, off, 64);
            bool t = (ok < mk) || (ok == mk && oi < mi);
            mk = t ? ok : mk; mi = t ? oi : mi;
        }
        bool win = (ks[0] == mk) && (ti[0] == mi);
        #pragma unroll
        for (int q = 0; q < LK - 1; ++q) {
            ks[q] = win ? ks[q+1] : ks[q];
            ti[q] = win ? ti[q+1] : ti[q];
        }
        ks[LK-1] = win ? 0xFFFFFFFFu : ks[LK-1];
        ti[LK-1] = win ? IMAX : ti[LK-1];
        if (lane == r) { sk[wave * NCF + r] = mk; sc[wave * NCF + r] = mi; }
    }
    __syncthreads();
    // phase C: wave 0 merges 64 -> exact top-16
    if (wave == 0) {
        unsigned myk = sk[lane];
        int      myc = sc[lane];
        #pragma unroll
        for (int r = 0; r < NCF; ++r) {
            unsigned mk = myk; int mi = myc;
            #pragma unroll
            for (int off = 1; off < 64; off <<= 1) {
                unsigned ok = (unsigned)__shfl_xor((int)mk, off, 64);
                int      oi = __shfl_xor(mi, off, 64);
                bool t = (ok < mk) || (ok == mk && oi < mi);
                mk = t ? ok : mk; mi = t ? oi : mi;
            }
            bool win = (myk == mk) && (myc == mi);
            myk = win ? 0xFFFFFFFFu : myk;
            myc = win ? IMAX : myc;
            if (lane == r) ids[r] = mi;
        }
    }
    __syncthreads();
    // phase D: exact fp32 rescore of 16 candidates
    float4 q0 = *(const float4*)(Q + (size_t)row * DD + lane * 8);
    float4 q1 = *(const float4*)(Q + (size_t)row * DD + lane * 8 + 4);
    for (int c = wave; c < NCF; c += 4) {
        int j = ids[c];
        const float* mr = Mm + (size_t)j * DD;
        float4 m0 = *(const float4*)(mr + lane * 8);
        float4 m1 = *(const float4*)(mr + lane * 8 + 4);
        float dot = q0.x*m0.x + q0.y*m0.y + q0.z*m0.z + q0.w*m0.w
                  + q1.x*m1.x + q1.y*m1.y + q1.z*m1.z + q1.w*m1.w;
        #pragma unroll
        for (int off = 32; off; off >>= 1) dot += __shfl_xor(dot, off, 64);
        if (lane == 0) d2s[c] = fmaf(-2.f, dot, mnorm[j]);
    }
    __syncthreads();
    // phase E: top-10 (exact lexicographic)
    if (threadIdx.x == 0) {
        float ts[TOPN]; int tj[TOPN];
        #pragma unroll
        for (int p = 0; p < TOPN; ++p) { ts[p] = FINF; tj[p] = IMAX; }
        for (int c = 0; c < NCF; ++c) topk_insert<TOPN>(ts, tj, d2s[c], ids[c]);
        #pragma unroll
        for (int p = 0; p < TOPN; ++p) knn_idx[row * TOPN + p] = tj[p];
    }
}

// ---------------- unified bf16 MFMA GEMM (m97 structure, swizzled LDS) ----------------
template<int ACT, int OUT_BF16>
__global__ __launch_bounds__(256) void gemm_bf16_nt(
        const unsigned short* __restrict__ A,
        const unsigned short* __restrict__ B,
        const float* __restrict__ bias,
        void* __restrict__ Cout, int ldc) {
    __shared__ __align__(16) unsigned short As[128 * 64];
    __shared__ __align__(16) unsigned short Bs[128 * 64];
    const int tid  = threadIdx.x;
    const int wave = tid >> 6, lane = tid & 63;
    const int quad = lane >> 4, c16 = lane & 15;
    const int m0 = blockIdx.y * 128, n0 = blockIdx.x * 128;
    const int wm0 = (wave >> 1) * 64, wn0 = (wave & 1) * 64;
    const int srow = wave * 32 + (lane >> 3);
    const int schunk = (lane & 7) ^ ((lane >> 3) & 7);
    const int xsw = c16 & 7;

    f32x4 acc[4][4] = {};

    for (int kt = 0; kt < DD; kt += 64) {
        __syncthreads();
        #pragma unroll
        for (int i = 0; i < 4; ++i) {
            const unsigned short* ga = A + (size_t)(m0 + srow + i * 8) * DD + kt + schunk * 8;
            async_copy16(ga, &As[(wave * 32 + i * 8) * 64]);
            const unsigned short* gb = B + (size_t)(n0 + srow + i * 8) * DD + kt + schunk * 8;
            async_copy16(gb, &Bs[(wave * 32 + i * 8) * 64]);
        }
        __syncthreads();
        #pragma unroll
        for (int ks = 0; ks < 64; ks += 32) {
            const int coff = (((ks >> 3) + quad) ^ xsw) << 3;
            bf16x8 af[4], bff[4];
            #pragma unroll
            for (int mt = 0; mt < 4; ++mt)
                af[mt] = *(const bf16x8*)&As[(wm0 + mt * 16 + c16) * 64 + coff];
            #pragma unroll
            for (int nt = 0; nt < 4; ++nt)
                bff[nt] = *(const bf16x8*)&Bs[(wn0 + nt * 16 + c16) * 64 + coff];
            #pragma unroll
            for (int mt = 0; mt < 4; ++mt)
                #pragma unroll
                for (int nt = 0; nt < 4; ++nt)
                    acc[mt][nt] = __builtin_amdgcn_mfma_f32_16x16x32_bf16(
                        af[mt], bff[nt], acc[mt][nt], 0, 0, 0);
        }
    }
    #pragma unroll
    for (int nt = 0; nt < 4; ++nt) {
        int ncol = n0 + wn0 + nt * 16 + c16;
        float bv = bias[ncol];
        #pragma unroll
        for (int mt = 0; mt < 4; ++mt) {
            size_t rbase = (size_t)(m0 + wm0 + mt * 16 + quad * 4) * ldc + ncol;
            #pragma unroll
            for (int r = 0; r < 4; ++r) {
                float v = acc[mt][nt][r] + bv;
                if (ACT == 1) v = v >= 0.f ? v : 0.01f * v;
                if (OUT_BF16) ((unsigned short*)Cout)[rbase + (size_t)r * ldc] = f2bf(v);
                else          ((float*)Cout)[rbase + (size_t)r * ldc] = v;
            }
        }
    }
}

// ---------------- K/V/q projections in ONE dispatch (compacted y-grid) ----------------
// y in [0,256) -> K; [256,512) -> V; [512,544) -> q.  No dead blocks.
struct G3 {
    const unsigned short* A[3];
    const unsigned short* B[3];
    const float* bias[3];
    void* C[3];
    int obf[3];
};
__global__ __launch_bounds__(256) void gemm3_kernel(G3 g) {
    const int yy = blockIdx.y;
    const int z = (yy >= 512) ? 2 : (yy >= 256 ? 1 : 0);
    const int my = yy - z * 256;
    __shared__ __align__(16) unsigned short As[128 * 64];
    __shared__ __align__(16) unsigned short Bs[128 * 64];
    const unsigned short* A = g.A[z];
    const unsigned short* B = g.B[z];
    const int tid  = threadIdx.x;
    const int wave = tid >> 6, lane = tid & 63;
    const int quad = lane >> 4, c16 = lane & 15;
    const int m0 = my * 128, n0 = blockIdx.x * 128;
    const int wm0 = (wave >> 1) * 64, wn0 = (wave & 1) * 64;
    const int srow = wave * 32 + (lane >> 3);
    const int schunk = (lane & 7) ^ ((lane >> 3) & 7);
    const int xsw = c16 & 7;

    f32x4 acc[4][4] = {};

    for (int kt = 0; kt < DD; kt += 64) {
        __syncthreads();
        #pragma unroll
        for (int i = 0; i < 4; ++i) {
            const unsigned short* ga = A + (size_t)(m0 + srow + i * 8) * DD + kt + schunk * 8;
            async_copy16(ga, &As[(wave * 32 + i * 8) * 64]);
            const unsigned short* gb = B + (size_t)(n0 + srow + i * 8) * DD + kt + schunk * 8;
            async_copy16(gb, &Bs[(wave * 32 + i * 8) * 64]);
        }
        __syncthreads();
        #pragma unroll
        for (int ks = 0; ks < 64; ks += 32) {
            const int coff = (((ks >> 3) + quad) ^ xsw) << 3;
            bf16x8 af[4], bff[4];
            #pragma unroll
            for (int mt = 0; mt < 4; ++mt)
                af[mt] = *(const bf16x8*)&As[(wm0 + mt * 16 + c16) * 64 + coff];
            #pragma unroll
            for (int nt = 0; nt < 4; ++nt)
                bff[nt] = *(const bf16x8*)&Bs[(wn0 + nt * 16 + c16) * 64 + coff];
            #pragma unroll
            for (int mt = 0; mt < 4; ++mt)
                #pragma unroll
                for (int nt = 0; nt < 4; ++nt)
                    acc[mt][nt] = __builtin_amdgcn_mfma_f32_16x16x32_bf16(
                        af[mt], bff[nt], acc[mt][nt], 0, 0, 0);
        }
    }
    const int obf = g.obf[z];
    #pragma unroll
    for (int nt = 0; nt < 4; ++nt) {
        int ncol = n0 + wn0 + nt * 16 + c16;
        float bv = g.bias[z][ncol];
        #pragma unroll
        for (int mt = 0; mt < 4; ++mt) {
            size_t rbase = (size_t)(m0 + wm0 + mt * 16 + quad * 4) * DD + ncol;
            #pragma unroll
            for (int r = 0; r < 4; ++r) {
                float v = acc[mt][nt][r] + bv;
                if (obf) ((unsigned short*)g.C[z])[rbase + (size_t)r * DD] = f2bf(v);
                else     ((float*)g.C[z])[rbase + (size_t)r * DD] = v;
            }
        }
    }
}

// ---------------- attention: one block per query row, one wave per head ----------------
__global__ __launch_bounds__(512) void attn_kernel(
        const float* __restrict__ qh, const unsigned short* __restrict__ Kall,
        const unsigned short* __restrict__ Vall, const int* __restrict__ knn_idx,
        unsigned short* __restrict__ ctx_b) {
    const int b = blockIdx.x;
    const int h = threadIdx.x >> 6;
    const int l = threadIdx.x & 63;
    const int col = (h << 6) + l;
    int idxs[TOPN];
    #pragma unroll
    for (int n = 0; n < TOPN; ++n) idxs[n] = knn_idx[b * TOPN + n];
    const float q = qh[(size_t)b * DD + col];
    float sc[TOPN];
    #pragma unroll
    for (int n = 0; n < TOPN; ++n) {
        float p = q * __uint_as_float((unsigned)Kall[(size_t)idxs[n] * DD + col] << 16);
        #pragma unroll
        for (int off = 32; off; off >>= 1) p += __shfl_xor(p, off, 64);
        sc[n] = p * 0.125f;
    }
    float mx = sc[0];
    #pragma unroll
    for (int n = 1; n < TOPN; ++n) mx = fmaxf(mx, sc[n]);
    float se = 0.f;
    #pragma unroll
    for (int n = 0; n < TOPN; ++n) { sc[n] = expf(sc[n] - mx); se += sc[n]; }
    const float inv = 1.f / se;
    float o = 0.f;
    #pragma unroll
    for (int n = 0; n < TOPN; ++n)
        o = fmaf(sc[n] * inv,
                 __uint_as_float((unsigned)Vall[(size_t)idxs[n] * DD + col] << 16), o);
    ctx_b[(size_t)b * DD + col] = f2bf(o);
}

// ---------------- residual add + layernorm (optional bf16 secondary output) ----------------
template<int EMIT_BF16>
__global__ __launch_bounds__(256) void add_ln_kernel(
        const float* __restrict__ X, const float* __restrict__ Y,
        const float* __restrict__ g, const float* __restrict__ be,
        float* __restrict__ out, unsigned short* __restrict__ out_b) {
    const int row = blockIdx.x;
    const int t = threadIdx.x;
    const size_t base = (size_t)row * DD;
    float v0 = X[base + t]       + Y[base + t];
    float v1 = X[base + 256 + t] + Y[base + 256 + t];
    float s = v0 + v1, sq = v0 * v0 + v1 * v1;
    #pragma unroll
    for (int off = 32; off; off >>= 1) { s += __shfl_xor(s, off, 64); sq += __shfl_xor(sq, off, 64); }
    __shared__ float rs[4], rq[4];
    const int w = t >> 6, l = t & 63;
    if (l == 0) { rs[w] = s; rq[w] = sq; }
    __syncthreads();
    float tot  = rs[0] + rs[1] + rs[2] + rs[3];
    float totq = rq[0] + rq[1] + rq[2] + rq[3];
    float mu = tot * (1.f / DD);
    float var = totq * (1.f / DD) - mu * mu;
    float rstd = rsqrtf(var + 1e-5f);
    float o0 = (v0 - mu) * rstd * g[t]       + be[t];
    float o1 = (v1 - mu) * rstd * g[256 + t] + be[256 + t];
    out[base + t] = o0;
    out[base + 256 + t] = o1;
    if (EMIT_BF16) {
        out_b[base + t] = f2bf(o0);
        out_b[base + 256 + t] = f2bf(o1);
    }
}

// ---------------- launch ----------------
extern "C" void kernel_launch(void* const* d_in, const int* in_sizes, int n_in,
                              void* d_out, int out_size, void* d_ws, size_t ws_size,
                              hipStream_t stream) {
    const float* visit = (const float*)d_in[0];
    const float* Epat  = (const float*)d_in[1];
    const float* Emed  = (const float*)d_in[2];
    const float* Wq = (const float*)d_in[3];
    const float* Wk = (const float*)d_in[4];
    const float* Wv = (const float*)d_in[5];
    const float* bq = (const float*)d_in[6];
    const float* bk = (const float*)d_in[7];
    const float* bv = (const float*)d_in[8];
    const float* Wo = (const float*)d_in[9];
    const float* bo = (const float*)d_in[10];
    const float* W1 = (const float*)d_in[11];
    const float* b1 = (const float*)d_in[12];
    const float* W2 = (const float*)d_in[13];
    const float* b2 = (const float*)d_in[14];
    const float* ln1g = (const float*)d_in[15];
    const float* ln1b = (const float*)d_in[16];
    const float* ln2g = (const float*)d_in[17];
    const float* ln2b = (const float*)d_in[18];
    float* out = (float*)d_out;

    // ---- workspace layout, ~174 MB peak ----
    char* base = (char*)d_ws;
    const size_t MB = 1u << 20;
    float* mnorm   = (float*)(base);                    // 128 KB
    int*   knn_idx = (int*)  (base + 2*MB);             // 160 KB
    float* qh      = (float*)(base + 3*MB);             // 8 MB
    float* attn_o  = qh;                                // alias: qh dead after attn
    float* x1      = (float*)(base + 11*MB);            // 8 MB
    float* ff      = (float*)(base + 19*MB);            // 8 MB
    unsigned short* Qb    = (unsigned short*)(base + 27*MB);  // 4 MB (visit bf16)
    unsigned short* ctx_b = (unsigned short*)(base + 31*MB);  // 4 MB
    unsigned short* x1_b  = (unsigned short*)(base + 35*MB);  // 4 MB
    unsigned short* h1_b  = (unsigned short*)(base + 39*MB);  // 4 MB
    unsigned short* Wq_b  = (unsigned short*)(base + 43*MB);  // 6 x 512 KB
    unsigned short* Wk_b  = Wq_b + 262144;
    unsigned short* Wv_b  = Wk_b + 262144;
    unsigned short* Wo_b  = Wv_b + 262144;
    unsigned short* W1_b  = Wo_b + 262144;
    unsigned short* W2_b  = W1_b + 262144;
    unsigned short* Mb     = (unsigned short*)(base + 46*MB); // 32 MB (Epat bf16)
    unsigned short* Emed_b = (unsigned short*)(base + 78*MB); // 32 MB
    // K|V region (64 MB bf16); cand_part (32 MB) aliases Kall during kNN phase
    unsigned short* Kall = (unsigned short*)(base + 110*MB);  // 32 MB
    unsigned short* Vall = Kall + (size_t)NMEM * DD;          // 32 MB
    unsigned* cand_part = (unsigned*)Kall;                    // alias (kNN only)

    // ---- casts + norms (2 dispatches total) ----
    cast_norm2_kernel<<<dim3(NMEM / 4, 2), 256, 0, stream>>>(Epat, Mb, Emed, Emed_b, mnorm);
    CastDesc cd;
    cd.in[0] = visit; cd.out[0] = Qb;
    cd.in[1] = Wq; cd.in[2] = Wk; cd.in[3] = Wv; cd.in[4] = Wo; cd.in[5] = W1; cd.in[6] = W2;
    cd.out[1] = Wq_b; cd.out[2] = Wk_b; cd.out[3] = Wv_b; cd.out[4] = Wo_b; cd.out[5] = W1_b; cd.out[6] = W2_b;
    cd.start[0] = 0; cd.start[1] = 2048;
    for (int s = 2; s <= 7; ++s) cd.start[s] = cd.start[s-1] + 256;
    cast_multi_kernel<<<cd.start[7], 256, 0, stream>>>(cd);

    // ---- kNN: fused MFMA scores + selection -> fused merge+rescore ----
    gemm_knn_kernel<<<dim3(CB, BQ / 128), 256, 0, stream>>>(Qb, Mb, mnorm, cand_part);
    knn_select_kernel<<<BQ, 256, 0, stream>>>(cand_part, visit, Epat, mnorm, knn_idx);

    // ---- K/V/q projections in one compacted dispatch (Kall write overwrites cand_part)
    G3 g3;
    g3.A[0] = Mb;     g3.B[0] = Wk_b; g3.bias[0] = bk; g3.C[0] = Kall; g3.obf[0] = 1;
    g3.A[1] = Emed_b; g3.B[1] = Wv_b; g3.bias[1] = bv; g3.C[1] = Vall; g3.obf[1] = 1;
    g3.A[2] = Qb;     g3.B[2] = Wq_b; g3.bias[2] = bq; g3.C[2] = qh;   g3.obf[2] = 0;
    gemm3_kernel<<<dim3(4, 544), 256, 0, stream>>>(g3);

    attn_kernel<<<BQ, 512, 0, stream>>>(qh, Kall, Vall, knn_idx, ctx_b);

    gemm_bf16_nt<0,0><<<dim3(4, BQ / 128), 256, 0, stream>>>(ctx_b, Wo_b, bo, attn_o, DD);
    add_ln_kernel<1><<<BQ, 256, 0, stream>>>(visit, attn_o, ln1g, ln1b, x1, x1_b);
    gemm_bf16_nt<1,1><<<dim3(4, BQ / 128), 256, 0, stream>>>(x1_b, W1_b, b1, h1_b, DD);
    gemm_bf16_nt<0,0><<<dim3(4, BQ / 128), 256, 0, stream>>>(h1_b, W2_b, b2, ff,   DD);
    add_ln_kernel<0><<<BQ, 256, 0, stream>>>(x1, ff, ln2g, ln2b, out, nullptr);
}